// Round 1
// baseline (609.183 us; speedup 1.0000x reference)
//
#include <hip/hip_runtime.h>
#include <cmath>

#define B_   4
#define H_   16
#define KVH_ 4
#define D_   256
#define HID_ 4096
#define PAST_ 8191
#define S_   8192
#define KKEEP_ 2048
#define R_   128

// workspace layout (float offsets)
#define OFF_Q     0         // B*H*D = 16384
#define OFF_KN    16384     // B*KVH*D = 4096
#define OFF_VN    20480     // 4096
#define OFF_SCALE 24576     // 64
#define OFF_CMASK 24640     // 512 uint32 slots
#define OFF_F     32768     // B*H*S = 524288
#define OFF_A     557056    // 524288
#define OFF_P     1081344   // 524288
#define OFF_YP    1605632   // 32*16*4*256 = 524288
#define OFF_Y     2129920   // 16384

// ---------------- K1: QKV GEMV + RoPE ----------------
// grid = 24 slots * 128 d-pairs = 3072 blocks, 256 threads
__global__ __launch_bounds__(256) void k1_qkv(
    const float* __restrict__ hidden, const int* __restrict__ pos_ids,
    const float* __restrict__ Wq, const float* __restrict__ Wk, const float* __restrict__ Wv,
    float* __restrict__ q_ws, float* __restrict__ knew, float* __restrict__ vnew)
{
    int slot = blockIdx.x >> 7;
    int d    = blockIdx.x & 127;
    const float* W; float* outp; int head; bool rope; int bstride;
    if (slot < 16)      { W = Wq; head = slot;      outp = q_ws + head * D_; rope = true;  bstride = H_ * D_; }
    else if (slot < 20) { W = Wk; head = slot - 16; outp = knew + head * D_; rope = true;  bstride = KVH_ * D_; }
    else                { W = Wv; head = slot - 20; outp = vnew + head * D_; rope = false; bstride = KVH_ * D_; }

    int rowbase = head * D_ + d;
    const float* w0 = W + (size_t)rowbase * HID_;
    const float* w1 = W + (size_t)(rowbase + 128) * HID_;

    float acc0[4] = {0.f, 0.f, 0.f, 0.f};
    float acc1[4] = {0.f, 0.f, 0.f, 0.f};
#pragma unroll
    for (int i = 0; i < 4; ++i) {
        int c = (threadIdx.x + 256 * i) * 4;
        float4 a0 = *(const float4*)(w0 + c);
        float4 a1 = *(const float4*)(w1 + c);
#pragma unroll
        for (int b = 0; b < 4; ++b) {
            float4 hv = *(const float4*)(hidden + b * HID_ + c);
            acc0[b] += a0.x * hv.x + a0.y * hv.y + a0.z * hv.z + a0.w * hv.w;
            acc1[b] += a1.x * hv.x + a1.y * hv.y + a1.z * hv.z + a1.w * hv.w;
        }
    }
#pragma unroll
    for (int off = 1; off < 64; off <<= 1) {
#pragma unroll
        for (int b = 0; b < 4; ++b) {
            acc0[b] += __shfl_xor(acc0[b], off, 64);
            acc1[b] += __shfl_xor(acc1[b], off, 64);
        }
    }
    __shared__ float red[4][8];
    int wv = threadIdx.x >> 6, ln = threadIdx.x & 63;
    if (ln == 0) {
#pragma unroll
        for (int b = 0; b < 4; ++b) { red[wv][b] = acc0[b]; red[wv][4 + b] = acc1[b]; }
    }
    __syncthreads();
    if (threadIdx.x == 0) {
        float x = (float)d * (1.0f / 128.0f);
        float invf = 1.0f / powf(10000.0f, x);
        for (int b = 0; b < 4; ++b) {
            float s0 = red[0][b] + red[1][b] + red[2][b] + red[3][b];
            float s1 = red[0][4 + b] + red[1][4 + b] + red[2][4 + b] + red[3][4 + b];
            float o0, o1;
            if (rope) {
                float ang = (float)pos_ids[b] * invf;   // float mult matches np outer
                double ad = (double)ang;
                float c = (float)cos(ad), sn = (float)sin(ad);
                o0 = s0 * c - s1 * sn;
                o1 = s1 * c + s0 * sn;
            } else { o0 = s0; o1 = s1; }
            outp[b * bstride + d]       = o0;
            outp[b * bstride + d + 128] = o1;
        }
    }
}

// ---------------- K1b: top-128 channel selection per (b,h) ----------------
__global__ __launch_bounds__(256) void k1b_chan(
    const float* __restrict__ q_ws, float* __restrict__ scale_ws, unsigned* __restrict__ cmask_ws)
{
    int bh = blockIdx.x;
    int t  = threadIdx.x;
    __shared__ unsigned ua[256];
    __shared__ float red[256];
    __shared__ unsigned bm[8];
    __shared__ float s_all;

    float qv = q_ws[bh * 256 + t];
    float aq = fabsf(qv);
    ua[t] = __float_as_uint(aq);   // non-negative floats: uint order == float order
    if (t < 8) bm[t] = 0u;
    __syncthreads();

    unsigned mine = ua[t];
    int rank = 0;
    for (int i = 0; i < 256; ++i) {
        unsigned o = ua[i];
        rank += (o > mine) || (o == mine && i < t);
    }
    bool kept = rank < R_;
    if (kept) atomicOr(&bm[t >> 5], 1u << (t & 31));

    red[t] = aq; __syncthreads();
    for (int off = 128; off; off >>= 1) { if (t < off) red[t] += red[t + off]; __syncthreads(); }
    if (t == 0) s_all = red[0];
    __syncthreads();
    red[t] = kept ? aq : 0.f; __syncthreads();
    for (int off = 128; off; off >>= 1) { if (t < off) red[t] += red[t + off]; __syncthreads(); }
    if (t == 0) scale_ws[bh] = sqrtf(256.0f * red[0] / s_all);
    if (t < 8) cmask_ws[bh * 8 + t] = bm[t];
}

// ---------------- K2: full + approx scores ----------------
// grid = 16 (b,kvh) * 32 chunks; block 256; one wave handles a K row,
// split into 4 groups of 16 lanes (one group per query head of the GQA group).
__global__ __launch_bounds__(256) void k2_scores(
    const float* __restrict__ past_key, const float* __restrict__ knew,
    const float* __restrict__ q_ws, const float* __restrict__ scale_ws,
    const unsigned* __restrict__ cmask_ws, const float* __restrict__ amask,
    float* __restrict__ fsc, float* __restrict__ asc)
{
    const int NCH = 32;
    int bkv = blockIdx.x / NCH;
    int chunk = blockIdx.x - bkv * NCH;
    int b = bkv >> 2, kvh = bkv & 3;
    int w = threadIdx.x >> 6, lane = threadIdx.x & 63;
    int g = lane >> 4, m = lane & 15;
    int h = kvh * 4 + g;

    const float* qp = q_ws + (b * H_ + h) * D_;
    const unsigned* cm = cmask_ws + (b * H_ + h) * 8;
    float inv_scale = 1.0f / scale_ws[b * H_ + h];

    float qr[16], ar[16];
#pragma unroll
    for (int i = 0; i < 4; ++i)
#pragma unroll
        for (int t = 0; t < 4; ++t) {
            int c = i * 64 + m * 4 + t;
            float q = qp[c];
            qr[i * 4 + t] = q;
            ar[i * 4 + t] = ((cm[c >> 5] >> (c & 31)) & 1u) ? q : 0.f;
        }

    const float* kbase = past_key + (size_t)(b * KVH_ + kvh) * PAST_ * D_;
    const float* knrow = knew + (b * KVH_ + kvh) * D_;
    float* fout = fsc + (size_t)(b * H_ + h) * S_;
    float* aout = asc + (size_t)(b * H_ + h) * S_;
    const float* mrow = amask + b * S_;
    int s0 = chunk * 256 + w;

    for (int it = 0; it < 64; ++it) {
        int s = s0 + it * 4;
        const float* krow = (s < PAST_) ? (kbase + (size_t)s * D_) : knrow;
        float full = 0.f, appr = 0.f;
#pragma unroll
        for (int i = 0; i < 4; ++i) {
            float4 kv = *(const float4*)(krow + i * 64 + m * 4);
            full += qr[i*4+0]*kv.x + qr[i*4+1]*kv.y + qr[i*4+2]*kv.z + qr[i*4+3]*kv.w;
            appr += ar[i*4+0]*kv.x + ar[i*4+1]*kv.y + ar[i*4+2]*kv.z + ar[i*4+3]*kv.w;
        }
#pragma unroll
        for (int off = 1; off < 16; off <<= 1) {
            full += __shfl_xor(full, off, 64);
            appr += __shfl_xor(appr, off, 64);
        }
        if (m == 0)      fout[s] = full * 0.0625f + mrow[s];
        else if (m == 1) aout[s] = appr * inv_scale + mrow[s];
    }
}

// ---------------- K3: radix-select top-2048 + softmax -> probs ----------------
__global__ __launch_bounds__(256) void k3_select(
    const float* __restrict__ fsc, const float* __restrict__ asc, float* __restrict__ probs)
{
    int bh = blockIdx.x;
    int t  = threadIdx.x;
    __shared__ unsigned ua[8192];
    __shared__ unsigned hist[256];
    __shared__ int eqs[256];
    __shared__ float mz[256], zz[256];
    __shared__ unsigned sh_prefix; __shared__ int sh_rem;
    __shared__ float sh_M, sh_Z;

    const float* ap = asc + (size_t)bh * S_;
    const float* fp = fsc + (size_t)bh * S_;

    for (int i = 0; i < 32; ++i) {
        int s = t + 256 * i;
        unsigned u = __float_as_uint(ap[s]);
        u ^= (u & 0x80000000u) ? 0xFFFFFFFFu : 0x80000000u;  // order-preserving map
        ua[s] = u;
    }
    __syncthreads();

    unsigned prefix = 0; int rem = KKEEP_;
    for (int pass = 0; pass < 4; ++pass) {
        int shift = 24 - 8 * pass;
        hist[t] = 0;
        __syncthreads();
        for (int i = 0; i < 32; ++i) {
            unsigned u = ua[t * 32 + i];
            bool match = (pass == 0) || ((u >> (shift + 8)) == prefix);
            if (match) atomicAdd(&hist[(u >> shift) & 0xFFu], 1u);
        }
        __syncthreads();
        if (t == 0) {
            unsigned cum = 0; int bin;
            for (bin = 255; bin >= 0; --bin) { cum += hist[bin]; if ((int)cum >= rem) break; }
            sh_rem = rem - (int)(cum - hist[bin]);
            sh_prefix = (prefix << 8) | (unsigned)bin;
        }
        __syncthreads();
        prefix = sh_prefix; rem = sh_rem;
        __syncthreads();
    }
    unsigned ut = prefix; int Need = rem;

    // stable tie-break: exclusive prefix of equal-count by index
    int cnt = 0;
    for (int i = 0; i < 32; ++i) cnt += (ua[t * 32 + i] == ut);
    eqs[t] = cnt;
    __syncthreads();
    if (t == 0) { int run = 0; for (int j = 0; j < 256; ++j) { int c = eqs[j]; eqs[j] = run; run += c; } }
    __syncthreads();

    // online softmax over kept elements
    int eqb = eqs[t];
    float m = -__builtin_inff(), z = 0.f;
    for (int i = 0; i < 32; ++i) {
        int s = t * 32 + i;
        unsigned u = ua[s];
        bool kept;
        if (u == ut) { kept = (eqb < Need); eqb++; }
        else kept = (u > ut);
        if (kept) {
            float f = fp[s];
            if (f > m) { z = z * expf(m - f) + 1.f; m = f; }
            else       { z += expf(f - m); }
        }
    }
    mz[t] = m; zz[t] = z;
    __syncthreads();
    if (t == 0) {
        float M = -__builtin_inff(), Z = 0.f;
        for (int j = 0; j < 256; ++j) {
            float mj = mz[j], zj = zz[j];
            if (zj == 0.f) continue;
            if (mj > M) { Z = Z * expf(M - mj) + zj; M = mj; }
            else        { Z += zj * expf(mj - M); }
        }
        sh_M = M; sh_Z = Z;
    }
    __syncthreads();
    float M = sh_M, invZ = 1.0f / sh_Z;
    float* pp = probs + (size_t)bh * S_;
    eqb = eqs[t];
    for (int i = 0; i < 32; ++i) {
        int s = t * 32 + i;
        unsigned u = ua[s];
        bool kept;
        if (u == ut) { kept = (eqb < Need); eqb++; }
        else kept = (u > ut);
        pp[s] = kept ? expf(fp[s] - M) * invZ : 0.f;
    }
}

// ---------------- K4: weighted V partial sums ----------------
__global__ __launch_bounds__(256) void k4_wv(
    const float* __restrict__ past_value, const float* __restrict__ vnew,
    const float* __restrict__ probs, float* __restrict__ ypart)
{
    const int NCH = 32;
    int bkv = blockIdx.x / NCH, chunk = blockIdx.x - bkv * NCH;
    int b = bkv >> 2, kvh = bkv & 3;
    int w = threadIdx.x >> 6, lane = threadIdx.x & 63;
    int h0 = kvh * 4;

    const float* p0 = probs + (size_t)(b * H_ + h0) * S_;
    const float* vbase = past_value + (size_t)(b * KVH_ + kvh) * PAST_ * D_;
    const float* vnrow = vnew + (b * KVH_ + kvh) * D_;

    float acc[4][4] = {{0.f}};
    int s0 = chunk * 256 + w;
    for (int it = 0; it < 64; ++it) {
        int s = s0 + it * 4;
        float pj0 = p0[s], pj1 = p0[S_ + s], pj2 = p0[2 * S_ + s], pj3 = p0[3 * S_ + s];
        if ((pj0 == 0.f) & (pj1 == 0.f) & (pj2 == 0.f) & (pj3 == 0.f)) continue;
        const float* vrow = (s < PAST_) ? (vbase + (size_t)s * D_) : vnrow;
        float4 vv = *(const float4*)(vrow + lane * 4);
        acc[0][0] += pj0 * vv.x; acc[0][1] += pj0 * vv.y; acc[0][2] += pj0 * vv.z; acc[0][3] += pj0 * vv.w;
        acc[1][0] += pj1 * vv.x; acc[1][1] += pj1 * vv.y; acc[1][2] += pj1 * vv.z; acc[1][3] += pj1 * vv.w;
        acc[2][0] += pj2 * vv.x; acc[2][1] += pj2 * vv.y; acc[2][2] += pj2 * vv.z; acc[2][3] += pj2 * vv.w;
        acc[3][0] += pj3 * vv.x; acc[3][1] += pj3 * vv.y; acc[3][2] += pj3 * vv.z; acc[3][3] += pj3 * vv.w;
    }

    __shared__ float part[4][4][256];   // [wave][head][dim]
#pragma unroll
    for (int j = 0; j < 4; ++j)
#pragma unroll
        for (int t4 = 0; t4 < 4; ++t4)
            part[w][j][lane * 4 + t4] = acc[j][t4];
    __syncthreads();

    float* yo = ypart + (size_t)(chunk * 16 + bkv) * 1024;
    for (int o = threadIdx.x; o < 1024; o += 256) {
        int j = o >> 8, d = o & 255;
        yo[o] = part[0][j][d] + part[1][j][d] + part[2][j][d] + part[3][j][d];
    }
}

// ---------------- K5: reduce partials -> y flat ----------------
__global__ __launch_bounds__(256) void k5_reduce(const float* __restrict__ ypart, float* __restrict__ yflat)
{
    int bh = blockIdx.x; int b = bh >> 4, h = bh & 15;
    int kvh = h >> 2, j = h & 3;
    int d = threadIdx.x;
    int bkv = b * 4 + kvh;
    float sum = 0.f;
    for (int c = 0; c < 32; ++c)
        sum += ypart[(size_t)(c * 16 + bkv) * 1024 + j * 256 + d];
    yflat[b * 4096 + h * 256 + d] = sum;
}

// ---------------- K6: output projection GEMV ----------------
__global__ __launch_bounds__(256) void k6_out(
    const float* __restrict__ Wo, const float* __restrict__ yflat, float* __restrict__ out)
{
    int i = blockIdx.x;
    const float* wrow = Wo + (size_t)i * HID_;
    float acc[4] = {0.f, 0.f, 0.f, 0.f};
#pragma unroll
    for (int ii = 0; ii < 4; ++ii) {
        int c = (threadIdx.x + 256 * ii) * 4;
        float4 wv = *(const float4*)(wrow + c);
#pragma unroll
        for (int b = 0; b < 4; ++b) {
            float4 yv = *(const float4*)(yflat + b * 4096 + c);
            acc[b] += wv.x * yv.x + wv.y * yv.y + wv.z * yv.z + wv.w * yv.w;
        }
    }
#pragma unroll
    for (int off = 1; off < 64; off <<= 1)
#pragma unroll
        for (int b = 0; b < 4; ++b) acc[b] += __shfl_xor(acc[b], off, 64);
    __shared__ float red[4][4];
    int wv_ = threadIdx.x >> 6, ln = threadIdx.x & 63;
    if (ln == 0)
#pragma unroll
        for (int b = 0; b < 4; ++b) red[wv_][b] = acc[b];
    __syncthreads();
    if (threadIdx.x < 4) {
        int b = threadIdx.x;
        out[b * HID_ + i] = red[0][b] + red[1][b] + red[2][b] + red[3][b];
    }
}

extern "C" void kernel_launch(void* const* d_in, const int* in_sizes, int n_in,
                              void* d_out, int out_size, void* d_ws, size_t ws_size,
                              hipStream_t stream)
{
    const float* hidden = (const float*)d_in[0];
    const float* amask  = (const float*)d_in[1];
    const int*   posids = (const int*)d_in[2];
    const float* pkey   = (const float*)d_in[3];
    const float* pval   = (const float*)d_in[4];
    const float* Wq     = (const float*)d_in[5];
    const float* Wk     = (const float*)d_in[6];
    const float* Wv     = (const float*)d_in[7];
    const float* Wo     = (const float*)d_in[8];
    float* out = (float*)d_out;
    float* ws  = (float*)d_ws;

    float* q_ws   = ws + OFF_Q;
    float* knew   = ws + OFF_KN;
    float* vnew   = ws + OFF_VN;
    float* scale  = ws + OFF_SCALE;
    unsigned* cmask = (unsigned*)(ws + OFF_CMASK);
    float* fsc    = ws + OFF_F;
    float* asc    = ws + OFF_A;
    float* probs  = ws + OFF_P;
    float* ypart  = ws + OFF_YP;
    float* yflat  = ws + OFF_Y;

    k1_qkv  <<<dim3(3072), dim3(256), 0, stream>>>(hidden, posids, Wq, Wk, Wv, q_ws, knew, vnew);
    k1b_chan<<<dim3(64),   dim3(256), 0, stream>>>(q_ws, scale, cmask);
    k2_scores<<<dim3(512), dim3(256), 0, stream>>>(pkey, knew, q_ws, scale, cmask, amask, fsc, asc);
    k3_select<<<dim3(64),  dim3(256), 0, stream>>>(fsc, asc, probs);
    k4_wv   <<<dim3(512),  dim3(256), 0, stream>>>(pval, vnew, probs, ypart);
    k5_reduce<<<dim3(64),  dim3(256), 0, stream>>>(ypart, yflat);
    k6_out  <<<dim3(4096), dim3(256), 0, stream>>>(Wo, yflat, out);
}

// Round 2
// 444.856 us; speedup vs baseline: 1.3694x; 1.3694x over previous
//
#include <hip/hip_runtime.h>
#include <cmath>

#define B_   4
#define H_   16
#define KVH_ 4
#define D_   256
#define HID_ 4096
#define PAST_ 8191
#define S_   8192
#define KKEEP_ 2048
#define R_   128

// workspace layout (float offsets)
#define OFF_Q     0         // B*H*D = 16384
#define OFF_KN    16384     // B*KVH*D = 4096
#define OFF_VN    20480     // 4096
#define OFF_SCALE 24576     // 64
#define OFF_CMASK 24640     // 512 uint32 slots
#define OFF_F     32768     // B*H*S = 524288
#define OFF_A     557056    // 524288
#define OFF_P     1081344   // 524288
#define OFF_YP    1605632   // 32*16*4*256 = 524288
#define OFF_Y     2129920   // 16384

// ---------------- K1: QKV GEMV + RoPE ----------------
__global__ __launch_bounds__(256) void k1_qkv(
    const float* __restrict__ hidden, const int* __restrict__ pos_ids,
    const float* __restrict__ Wq, const float* __restrict__ Wk, const float* __restrict__ Wv,
    float* __restrict__ q_ws, float* __restrict__ knew, float* __restrict__ vnew)
{
    int slot = blockIdx.x >> 7;
    int d    = blockIdx.x & 127;
    const float* W; float* outp; int head; bool rope; int bstride;
    if (slot < 16)      { W = Wq; head = slot;      outp = q_ws + head * D_; rope = true;  bstride = H_ * D_; }
    else if (slot < 20) { W = Wk; head = slot - 16; outp = knew + head * D_; rope = true;  bstride = KVH_ * D_; }
    else                { W = Wv; head = slot - 20; outp = vnew + head * D_; rope = false; bstride = KVH_ * D_; }

    int rowbase = head * D_ + d;
    const float* w0 = W + (size_t)rowbase * HID_;
    const float* w1 = W + (size_t)(rowbase + 128) * HID_;

    float acc0[4] = {0.f, 0.f, 0.f, 0.f};
    float acc1[4] = {0.f, 0.f, 0.f, 0.f};
#pragma unroll
    for (int i = 0; i < 4; ++i) {
        int c = (threadIdx.x + 256 * i) * 4;
        float4 a0 = *(const float4*)(w0 + c);
        float4 a1 = *(const float4*)(w1 + c);
#pragma unroll
        for (int b = 0; b < 4; ++b) {
            float4 hv = *(const float4*)(hidden + b * HID_ + c);
            acc0[b] += a0.x * hv.x + a0.y * hv.y + a0.z * hv.z + a0.w * hv.w;
            acc1[b] += a1.x * hv.x + a1.y * hv.y + a1.z * hv.z + a1.w * hv.w;
        }
    }
#pragma unroll
    for (int off = 1; off < 64; off <<= 1) {
#pragma unroll
        for (int b = 0; b < 4; ++b) {
            acc0[b] += __shfl_xor(acc0[b], off, 64);
            acc1[b] += __shfl_xor(acc1[b], off, 64);
        }
    }
    __shared__ float red[4][8];
    int wv = threadIdx.x >> 6, ln = threadIdx.x & 63;
    if (ln == 0) {
#pragma unroll
        for (int b = 0; b < 4; ++b) { red[wv][b] = acc0[b]; red[wv][4 + b] = acc1[b]; }
    }
    __syncthreads();
    if (threadIdx.x == 0) {
        float x = (float)d * (1.0f / 128.0f);
        float invf = 1.0f / powf(10000.0f, x);
        for (int b = 0; b < 4; ++b) {
            float s0 = red[0][b] + red[1][b] + red[2][b] + red[3][b];
            float s1 = red[0][4 + b] + red[1][4 + b] + red[2][4 + b] + red[3][4 + b];
            float o0, o1;
            if (rope) {
                float ang = (float)pos_ids[b] * invf;
                double ad = (double)ang;
                float c = (float)cos(ad), sn = (float)sin(ad);
                o0 = s0 * c - s1 * sn;
                o1 = s1 * c + s0 * sn;
            } else { o0 = s0; o1 = s1; }
            outp[b * bstride + d]       = o0;
            outp[b * bstride + d + 128] = o1;
        }
    }
}

// ---------------- K1b: top-128 channel selection per (b,h) ----------------
__global__ __launch_bounds__(256) void k1b_chan(
    const float* __restrict__ q_ws, float* __restrict__ scale_ws, unsigned* __restrict__ cmask_ws)
{
    int bh = blockIdx.x;
    int t  = threadIdx.x;
    __shared__ unsigned ua[256];
    __shared__ float red[256];
    __shared__ unsigned bm[8];
    __shared__ float s_all;

    float qv = q_ws[bh * 256 + t];
    float aq = fabsf(qv);
    ua[t] = __float_as_uint(aq);
    if (t < 8) bm[t] = 0u;
    __syncthreads();

    unsigned mine = ua[t];
    int rank = 0;
    for (int i = 0; i < 256; ++i) {
        unsigned o = ua[i];
        rank += (o > mine) || (o == mine && i < t);
    }
    bool kept = rank < R_;
    if (kept) atomicOr(&bm[t >> 5], 1u << (t & 31));

    red[t] = aq; __syncthreads();
    for (int off = 128; off; off >>= 1) { if (t < off) red[t] += red[t + off]; __syncthreads(); }
    if (t == 0) s_all = red[0];
    __syncthreads();
    red[t] = kept ? aq : 0.f; __syncthreads();
    for (int off = 128; off; off >>= 1) { if (t < off) red[t] += red[t + off]; __syncthreads(); }
    if (t == 0) scale_ws[bh] = sqrtf(256.0f * red[0] / s_all);
    if (t < 8) cmask_ws[bh * 8 + t] = bm[t];
}

// ---------------- K2: full + approx scores (prefetched) ----------------
// grid = 16 (b,kvh) * 64 chunks; block 256; one wave per K row,
// split into 4 groups of 16 lanes (one group per query head of the GQA group).
__global__ __launch_bounds__(256) void k2_scores(
    const float* __restrict__ past_key, const float* __restrict__ knew,
    const float* __restrict__ q_ws, const float* __restrict__ scale_ws,
    const unsigned* __restrict__ cmask_ws, const float* __restrict__ amask,
    float* __restrict__ fsc, float* __restrict__ asc)
{
    int bkv   = blockIdx.x >> 6;
    int chunk = blockIdx.x & 63;
    int b = bkv >> 2, kvh = bkv & 3;
    int w = threadIdx.x >> 6, lane = threadIdx.x & 63;
    int g = lane >> 4, m = lane & 15;
    int h = kvh * 4 + g;

    const float* qp = q_ws + (b * H_ + h) * D_;
    const unsigned* cm = cmask_ws + (b * H_ + h) * 8;
    float inv_scale = 1.0f / scale_ws[b * H_ + h];

    float qr[16], ar[16];
#pragma unroll
    for (int i = 0; i < 4; ++i)
#pragma unroll
        for (int t = 0; t < 4; ++t) {
            int c = i * 64 + m * 4 + t;
            float q = qp[c];
            qr[i * 4 + t] = q;
            ar[i * 4 + t] = ((cm[c >> 5] >> (c & 31)) & 1u) ? q : 0.f;
        }

    const float* kbase = past_key + (size_t)(b * KVH_ + kvh) * PAST_ * D_;
    const float* knrow = knew + (b * KVH_ + kvh) * D_;
    float* fout = fsc + (size_t)(b * H_ + h) * S_;
    float* aout = asc + (size_t)(b * H_ + h) * S_;
    const float* mrow = amask + b * S_;
    int s0 = chunk * 128 + w;

    const float* r0 = (s0 < PAST_) ? (kbase + (size_t)s0 * D_) : knrow;
    float4 n0 = *(const float4*)(r0 + m * 4);
    float4 n1 = *(const float4*)(r0 + 64 + m * 4);
    float4 n2 = *(const float4*)(r0 + 128 + m * 4);
    float4 n3 = *(const float4*)(r0 + 192 + m * 4);

    for (int it = 0; it < 32; ++it) {
        int s = s0 + it * 4;
        float4 c0 = n0, c1 = n1, c2 = n2, c3 = n3;
        if (it < 31) {
            int sn = s + 4;
            const float* rn = (sn < PAST_) ? (kbase + (size_t)sn * D_) : knrow;
            n0 = *(const float4*)(rn + m * 4);
            n1 = *(const float4*)(rn + 64 + m * 4);
            n2 = *(const float4*)(rn + 128 + m * 4);
            n3 = *(const float4*)(rn + 192 + m * 4);
        }
        float full = 0.f, appr = 0.f;
        full += qr[0]*c0.x + qr[1]*c0.y + qr[2]*c0.z + qr[3]*c0.w;
        appr += ar[0]*c0.x + ar[1]*c0.y + ar[2]*c0.z + ar[3]*c0.w;
        full += qr[4]*c1.x + qr[5]*c1.y + qr[6]*c1.z + qr[7]*c1.w;
        appr += ar[4]*c1.x + ar[5]*c1.y + ar[6]*c1.z + ar[7]*c1.w;
        full += qr[8]*c2.x + qr[9]*c2.y + qr[10]*c2.z + qr[11]*c2.w;
        appr += ar[8]*c2.x + ar[9]*c2.y + ar[10]*c2.z + ar[11]*c2.w;
        full += qr[12]*c3.x + qr[13]*c3.y + qr[14]*c3.z + qr[15]*c3.w;
        appr += ar[12]*c3.x + ar[13]*c3.y + ar[14]*c3.z + ar[15]*c3.w;
#pragma unroll
        for (int off = 1; off < 16; off <<= 1) {
            full += __shfl_xor(full, off, 64);
            appr += __shfl_xor(appr, off, 64);
        }
        if (m == 0)      fout[s] = full * 0.0625f + mrow[s];
        else if (m == 1) aout[s] = appr * inv_scale + mrow[s];
    }
}

// ---------------- K3: radix-select top-2048 + softmax -> probs ----------------
// 64 blocks (one per b,h), 1024 threads. Conflict-free padded LDS, per-wave
// histograms, shuffle scans.
#define PAD(s) ((s) + ((s) >> 5))
__global__ __launch_bounds__(1024) void k3_select(
    const float* __restrict__ fsc, const float* __restrict__ asc, float* __restrict__ probs)
{
    int bh = blockIdx.x;
    int t  = threadIdx.x;
    int lane = t & 63, wid = t >> 6;
    __shared__ unsigned ua[8448];        // 8192 + 256 pad words
    __shared__ unsigned hist2[16 * 257]; // per-wave histograms, row-padded
    __shared__ unsigned hist[256];
    __shared__ unsigned sf[256];
    __shared__ int wsum[16], wbase[16];
    __shared__ float wred[16];
    __shared__ unsigned sh_bin; __shared__ int sh_rem;
    __shared__ float sh_M, sh_Z;

    const float* ap = asc + (size_t)bh * S_;
    const float* fp = fsc + (size_t)bh * S_;

#pragma unroll
    for (int i = 0; i < 8; ++i) {
        int s = i * 1024 + t;
        unsigned u = __float_as_uint(ap[s]);
        u ^= (u & 0x80000000u) ? 0xFFFFFFFFu : 0x80000000u;  // order-preserving map
        ua[PAD(s)] = u;
    }

    unsigned prefix = 0; int rem = KKEEP_;
    for (int pass = 0; pass < 4; ++pass) {
        const int shift = 24 - 8 * pass;
        for (int j = t; j < 16 * 257; j += 1024) hist2[j] = 0;
        __syncthreads();
#pragma unroll
        for (int i = 0; i < 8; ++i) {
            unsigned u = ua[PAD(i * 1024 + t)];
            bool match = (pass == 0) || ((u >> (shift + 8)) == prefix);
            if (match) atomicAdd(&hist2[wid * 257 + ((u >> shift) & 255u)], 1u);
        }
        __syncthreads();
        if (t < 256) {
            unsigned hsum = 0;
#pragma unroll
            for (int w2 = 0; w2 < 16; ++w2) hsum += hist2[w2 * 257 + t];
            hist[t] = hsum;
        }
        __syncthreads();
        if (t < 64) {  // wave 0: suffix-sum of 256 bins via shuffles
            unsigned h0 = hist[t*4], h1 = hist[t*4+1], h2 = hist[t*4+2], h3 = hist[t*4+3];
            unsigned loc = h0 + h1 + h2 + h3;
            unsigned run = loc;
#pragma unroll
            for (int off = 1; off < 64; off <<= 1) {
                unsigned v = __shfl_down(run, off, 64);
                if (t + off < 64) run += v;
            }
            unsigned tail = run - loc;   // sum over lanes > me
            sf[t*4+3] = tail + h3;
            sf[t*4+2] = tail + h3 + h2;
            sf[t*4+1] = tail + h3 + h2 + h1;
            sf[t*4+0] = tail + loc;
        }
        __syncthreads();
        if (t < 256) {
            unsigned above = (t == 255) ? 0u : sf[t + 1];
            if (sf[t] >= (unsigned)rem && above < (unsigned)rem) {
                sh_bin = (unsigned)t;
                sh_rem = rem - (int)above;
            }
        }
        __syncthreads();
        prefix = (prefix << 8) | sh_bin;
        rem = sh_rem;
        __syncthreads();
    }
    unsigned ut = prefix; int Need = rem;

    // stable tie-break on contiguous per-thread chunks [t*8, t*8+8)
    int cnt = 0;
#pragma unroll
    for (int i = 0; i < 8; ++i)
        cnt += (ua[PAD(t * 8 + i)] == ut) ? 1 : 0;
    int inc = cnt;
#pragma unroll
    for (int off = 1; off < 64; off <<= 1) {
        int v = __shfl_up(inc, off, 64);
        if (lane >= off) inc += v;
    }
    if (lane == 63) wsum[wid] = inc;
    __syncthreads();
    if (t == 0) {
        int run = 0;
#pragma unroll
        for (int j = 0; j < 16; ++j) { int c = wsum[j]; wbase[j] = run; run += c; }
    }
    __syncthreads();
    int eqb = wbase[wid] + inc - cnt;   // exclusive index-ordered rank among ties
#pragma unroll
    for (int i = 0; i < 8; ++i) {
        int s = t * 8 + i;
        if (ua[PAD(s)] == ut) {
            ua[PAD(s)] = (eqb < Need) ? 0xFFFFFFFFu : 0u;  // sentinel keep/drop
            ++eqb;
        }
    }
    __syncthreads();

    // online softmax over kept elements (coalesced)
    float m = -3.4e38f, z = 0.f;
#pragma unroll
    for (int i = 0; i < 8; ++i) {
        int s = i * 1024 + t;
        if (ua[PAD(s)] > ut) {
            float f = fp[s];
            if (f > m) { z = z * expf(m - f) + 1.f; m = f; }
            else       { z += expf(f - m); }
        }
    }
    float wm = m;
#pragma unroll
    for (int off = 1; off < 64; off <<= 1) wm = fmaxf(wm, __shfl_xor(wm, off, 64));
    if (lane == 0) wred[wid] = wm;
    __syncthreads();
    if (t == 0) {
        float M = wred[0];
#pragma unroll
        for (int j = 1; j < 16; ++j) M = fmaxf(M, wred[j]);
        sh_M = M;
    }
    __syncthreads();
    float M = sh_M;
    float zs = z * expf(m - M);
#pragma unroll
    for (int off = 1; off < 64; off <<= 1) zs += __shfl_xor(zs, off, 64);
    if (lane == 0) wred[wid] = zs;
    __syncthreads();
    if (t == 0) {
        float Z = 0.f;
#pragma unroll
        for (int j = 0; j < 16; ++j) Z += wred[j];
        sh_Z = Z;
    }
    __syncthreads();
    float invZ = 1.0f / sh_Z;

    float* pp = probs + (size_t)bh * S_;
#pragma unroll
    for (int i = 0; i < 8; ++i) {
        int s = i * 1024 + t;
        pp[s] = (ua[PAD(s)] > ut) ? expf(fp[s] - M) * invZ : 0.f;
    }
}

// ---------------- K4: weighted V partial sums (prefetched streaming) ----------------
__global__ __launch_bounds__(256) void k4_wv(
    const float* __restrict__ past_value, const float* __restrict__ vnew,
    const float* __restrict__ probs, float* __restrict__ ypart)
{
    const int NCH = 32;
    int bkv = blockIdx.x / NCH, chunk = blockIdx.x - bkv * NCH;
    int b = bkv >> 2, kvh = bkv & 3;
    int w = threadIdx.x >> 6, lane = threadIdx.x & 63;
    int h0 = kvh * 4;

    const float* p0 = probs + (size_t)(b * H_ + h0) * S_;
    const float* vbase = past_value + (size_t)(b * KVH_ + kvh) * PAST_ * D_;
    const float* vnrow = vnew + (b * KVH_ + kvh) * D_;

    float acc[4][4] = {{0.f}};
    int s0 = chunk * 256 + w;

    const float* vr0 = (s0 < PAST_) ? (vbase + (size_t)s0 * D_) : vnrow;
    float4 vn = *(const float4*)(vr0 + lane * 4);
    float pn0 = p0[s0], pn1 = p0[S_ + s0], pn2 = p0[2 * S_ + s0], pn3 = p0[3 * S_ + s0];

    for (int it = 0; it < 64; ++it) {
        float4 vc = vn;
        float c0 = pn0, c1 = pn1, c2 = pn2, c3 = pn3;
        if (it < 63) {
            int sn = s0 + it * 4 + 4;
            const float* vrn = (sn < PAST_) ? (vbase + (size_t)sn * D_) : vnrow;
            vn = *(const float4*)(vrn + lane * 4);
            pn0 = p0[sn]; pn1 = p0[S_ + sn]; pn2 = p0[2 * S_ + sn]; pn3 = p0[3 * S_ + sn];
        }
        acc[0][0] += c0 * vc.x; acc[0][1] += c0 * vc.y; acc[0][2] += c0 * vc.z; acc[0][3] += c0 * vc.w;
        acc[1][0] += c1 * vc.x; acc[1][1] += c1 * vc.y; acc[1][2] += c1 * vc.z; acc[1][3] += c1 * vc.w;
        acc[2][0] += c2 * vc.x; acc[2][1] += c2 * vc.y; acc[2][2] += c2 * vc.z; acc[2][3] += c2 * vc.w;
        acc[3][0] += c3 * vc.x; acc[3][1] += c3 * vc.y; acc[3][2] += c3 * vc.z; acc[3][3] += c3 * vc.w;
    }

    __shared__ float part[4][4][256];   // [wave][head][dim]
#pragma unroll
    for (int j = 0; j < 4; ++j)
#pragma unroll
        for (int t4 = 0; t4 < 4; ++t4)
            part[w][j][lane * 4 + t4] = acc[j][t4];
    __syncthreads();

    float* yo = ypart + (size_t)(chunk * 16 + bkv) * 1024;
    for (int o = threadIdx.x; o < 1024; o += 256) {
        int j = o >> 8, d = o & 255;
        yo[o] = part[0][j][d] + part[1][j][d] + part[2][j][d] + part[3][j][d];
    }
}

// ---------------- K5: reduce partials -> y flat ----------------
__global__ __launch_bounds__(256) void k5_reduce(const float* __restrict__ ypart, float* __restrict__ yflat)
{
    int bh = blockIdx.x; int b = bh >> 4, h = bh & 15;
    int kvh = h >> 2, j = h & 3;
    int d = threadIdx.x;
    int bkv = b * 4 + kvh;
    float sum = 0.f;
    for (int c = 0; c < 32; ++c)
        sum += ypart[(size_t)(c * 16 + bkv) * 1024 + j * 256 + d];
    yflat[b * 4096 + h * 256 + d] = sum;
}

// ---------------- K6: output projection GEMV ----------------
__global__ __launch_bounds__(256) void k6_out(
    const float* __restrict__ Wo, const float* __restrict__ yflat, float* __restrict__ out)
{
    int i = blockIdx.x;
    const float* wrow = Wo + (size_t)i * HID_;
    float acc[4] = {0.f, 0.f, 0.f, 0.f};
#pragma unroll
    for (int ii = 0; ii < 4; ++ii) {
        int c = (threadIdx.x + 256 * ii) * 4;
        float4 wv = *(const float4*)(wrow + c);
#pragma unroll
        for (int b = 0; b < 4; ++b) {
            float4 yv = *(const float4*)(yflat + b * 4096 + c);
            acc[b] += wv.x * yv.x + wv.y * yv.y + wv.z * yv.z + wv.w * yv.w;
        }
    }
#pragma unroll
    for (int off = 1; off < 64; off <<= 1)
#pragma unroll
        for (int b = 0; b < 4; ++b) acc[b] += __shfl_xor(acc[b], off, 64);
    __shared__ float red[4][4];
    int wv_ = threadIdx.x >> 6, ln = threadIdx.x & 63;
    if (ln == 0)
#pragma unroll
        for (int b = 0; b < 4; ++b) red[wv_][b] = acc[b];
    __syncthreads();
    if (threadIdx.x < 4) {
        int b = threadIdx.x;
        out[b * HID_ + i] = red[0][b] + red[1][b] + red[2][b] + red[3][b];
    }
}

extern "C" void kernel_launch(void* const* d_in, const int* in_sizes, int n_in,
                              void* d_out, int out_size, void* d_ws, size_t ws_size,
                              hipStream_t stream)
{
    const float* hidden = (const float*)d_in[0];
    const float* amask  = (const float*)d_in[1];
    const int*   posids = (const int*)d_in[2];
    const float* pkey   = (const float*)d_in[3];
    const float* pval   = (const float*)d_in[4];
    const float* Wq     = (const float*)d_in[5];
    const float* Wk     = (const float*)d_in[6];
    const float* Wv     = (const float*)d_in[7];
    const float* Wo     = (const float*)d_in[8];
    float* out = (float*)d_out;
    float* ws  = (float*)d_ws;

    float* q_ws   = ws + OFF_Q;
    float* knew   = ws + OFF_KN;
    float* vnew   = ws + OFF_VN;
    float* scale  = ws + OFF_SCALE;
    unsigned* cmask = (unsigned*)(ws + OFF_CMASK);
    float* fsc    = ws + OFF_F;
    float* asc    = ws + OFF_A;
    float* probs  = ws + OFF_P;
    float* ypart  = ws + OFF_YP;
    float* yflat  = ws + OFF_Y;

    k1_qkv  <<<dim3(3072), dim3(256), 0, stream>>>(hidden, posids, Wq, Wk, Wv, q_ws, knew, vnew);
    k1b_chan<<<dim3(64),   dim3(256), 0, stream>>>(q_ws, scale, cmask);
    k2_scores<<<dim3(1024), dim3(256), 0, stream>>>(pkey, knew, q_ws, scale, cmask, amask, fsc, asc);
    k3_select<<<dim3(64),  dim3(1024), 0, stream>>>(fsc, asc, probs);
    k4_wv   <<<dim3(512),  dim3(256), 0, stream>>>(pval, vnew, probs, ypart);
    k5_reduce<<<dim3(64),  dim3(256), 0, stream>>>(ypart, yflat);
    k6_out  <<<dim3(4096), dim3(256), 0, stream>>>(Wo, yflat, out);
}

// Round 3
// 425.639 us; speedup vs baseline: 1.4312x; 1.0451x over previous
//
#include <hip/hip_runtime.h>
#include <cmath>

#define B_   4
#define H_   16
#define KVH_ 4
#define D_   256
#define HID_ 4096
#define PAST_ 8191
#define S_   8192
#define KKEEP_ 2048
#define R_   128

// workspace layout (float offsets)
#define OFF_Q     0         // B*H*D = 16384
#define OFF_KN    16384     // B*KVH*D = 4096
#define OFF_VN    20480     // 4096
#define OFF_SCALE 24576     // 64
#define OFF_CMASK 24640     // 512 uint32 slots
#define OFF_F     32768     // B*H*S = 524288
#define OFF_A     557056    // 524288
#define OFF_P     1081344   // 524288
#define OFF_YP    1605632   // 64*16*1024 = 1048576
#define OFF_Y     2654208   // 16384

// ---------------- K1: QKV GEMV + RoPE ----------------
__global__ __launch_bounds__(256) void k1_qkv(
    const float* __restrict__ hidden, const int* __restrict__ pos_ids,
    const float* __restrict__ Wq, const float* __restrict__ Wk, const float* __restrict__ Wv,
    float* __restrict__ q_ws, float* __restrict__ knew, float* __restrict__ vnew)
{
    int slot = blockIdx.x >> 7;
    int d    = blockIdx.x & 127;
    const float* W; float* outp; int head; bool rope; int bstride;
    if (slot < 16)      { W = Wq; head = slot;      outp = q_ws + head * D_; rope = true;  bstride = H_ * D_; }
    else if (slot < 20) { W = Wk; head = slot - 16; outp = knew + head * D_; rope = true;  bstride = KVH_ * D_; }
    else                { W = Wv; head = slot - 20; outp = vnew + head * D_; rope = false; bstride = KVH_ * D_; }

    int rowbase = head * D_ + d;
    const float* w0 = W + (size_t)rowbase * HID_;
    const float* w1 = W + (size_t)(rowbase + 128) * HID_;

    float acc0[4] = {0.f, 0.f, 0.f, 0.f};
    float acc1[4] = {0.f, 0.f, 0.f, 0.f};
#pragma unroll
    for (int i = 0; i < 4; ++i) {
        int c = (threadIdx.x + 256 * i) * 4;
        float4 a0 = *(const float4*)(w0 + c);
        float4 a1 = *(const float4*)(w1 + c);
#pragma unroll
        for (int b = 0; b < 4; ++b) {
            float4 hv = *(const float4*)(hidden + b * HID_ + c);
            acc0[b] += a0.x * hv.x + a0.y * hv.y + a0.z * hv.z + a0.w * hv.w;
            acc1[b] += a1.x * hv.x + a1.y * hv.y + a1.z * hv.z + a1.w * hv.w;
        }
    }
#pragma unroll
    for (int off = 1; off < 64; off <<= 1) {
#pragma unroll
        for (int b = 0; b < 4; ++b) {
            acc0[b] += __shfl_xor(acc0[b], off, 64);
            acc1[b] += __shfl_xor(acc1[b], off, 64);
        }
    }
    __shared__ float red[4][8];
    int wv = threadIdx.x >> 6, ln = threadIdx.x & 63;
    if (ln == 0) {
#pragma unroll
        for (int b = 0; b < 4; ++b) { red[wv][b] = acc0[b]; red[wv][4 + b] = acc1[b]; }
    }
    __syncthreads();
    if (threadIdx.x == 0) {
        float x = (float)d * (1.0f / 128.0f);
        float invf = 1.0f / powf(10000.0f, x);
        for (int b = 0; b < 4; ++b) {
            float s0 = red[0][b] + red[1][b] + red[2][b] + red[3][b];
            float s1 = red[0][4 + b] + red[1][4 + b] + red[2][4 + b] + red[3][4 + b];
            float o0, o1;
            if (rope) {
                float ang = (float)pos_ids[b] * invf;
                double ad = (double)ang;
                float c = (float)cos(ad), sn = (float)sin(ad);
                o0 = s0 * c - s1 * sn;
                o1 = s1 * c + s0 * sn;
            } else { o0 = s0; o1 = s1; }
            outp[b * bstride + d]       = o0;
            outp[b * bstride + d + 128] = o1;
        }
    }
}

// ---------------- K1b: top-128 channel selection per (b,h) ----------------
__global__ __launch_bounds__(256) void k1b_chan(
    const float* __restrict__ q_ws, float* __restrict__ scale_ws, unsigned* __restrict__ cmask_ws)
{
    int bh = blockIdx.x;
    int t  = threadIdx.x;
    __shared__ unsigned ua[256];
    __shared__ float red[256];
    __shared__ unsigned bm[8];
    __shared__ float s_all;

    float qv = q_ws[bh * 256 + t];
    float aq = fabsf(qv);
    ua[t] = __float_as_uint(aq);
    if (t < 8) bm[t] = 0u;
    __syncthreads();

    unsigned mine = ua[t];
    int rank = 0;
    for (int i = 0; i < 256; ++i) {
        unsigned o = ua[i];
        rank += (o > mine) || (o == mine && i < t);
    }
    bool kept = rank < R_;
    if (kept) atomicOr(&bm[t >> 5], 1u << (t & 31));

    red[t] = aq; __syncthreads();
    for (int off = 128; off; off >>= 1) { if (t < off) red[t] += red[t + off]; __syncthreads(); }
    if (t == 0) s_all = red[0];
    __syncthreads();
    red[t] = kept ? aq : 0.f; __syncthreads();
    for (int off = 128; off; off >>= 1) { if (t < off) red[t] += red[t + off]; __syncthreads(); }
    if (t == 0) scale_ws[bh] = sqrtf(256.0f * red[0] / s_all);
    if (t < 8) cmask_ws[bh * 8 + t] = bm[t];
}

// ---------------- K2: full + approx scores (2-row deep prefetch) ----------------
// grid = 16 (b,kvh) * 128 chunks of 64 rows; block 256; wave owns 16 contiguous
// rows, 2 rows/iteration; 4 groups of 16 lanes (one per query head).
__global__ __launch_bounds__(256) void k2_scores(
    const float* __restrict__ past_key, const float* __restrict__ knew,
    const float* __restrict__ q_ws, const float* __restrict__ scale_ws,
    const unsigned* __restrict__ cmask_ws, const float* __restrict__ amask,
    float* __restrict__ fsc, float* __restrict__ asc)
{
    int bkv   = blockIdx.x >> 7;
    int chunk = blockIdx.x & 127;
    int b = bkv >> 2, kvh = bkv & 3;
    int w = threadIdx.x >> 6, lane = threadIdx.x & 63;
    int g = lane >> 4, m = lane & 15;
    int h = kvh * 4 + g;

    const float* qp = q_ws + (b * H_ + h) * D_;
    const unsigned* cm = cmask_ws + (b * H_ + h) * 8;
    float inv_scale = 1.0f / scale_ws[b * H_ + h];

    float qr[16], ar[16];
#pragma unroll
    for (int i = 0; i < 4; ++i)
#pragma unroll
        for (int t = 0; t < 4; ++t) {
            int c = i * 64 + m * 4 + t;
            float q = qp[c];
            qr[i * 4 + t] = q;
            ar[i * 4 + t] = ((cm[c >> 5] >> (c & 31)) & 1u) ? q : 0.f;
        }

    const float* kbase = past_key + (size_t)(b * KVH_ + kvh) * PAST_ * D_;
    const float* knrow = knew + (b * KVH_ + kvh) * D_;
    float* fout = fsc + (size_t)(b * H_ + h) * S_;
    float* aout = asc + (size_t)(b * H_ + h) * S_;
    const float* mrow = amask + b * S_;
    int s0 = chunk * 64 + w * 16;   // wave owns rows [s0, s0+16)

    const float* rA = (s0     < PAST_) ? (kbase + (size_t)s0 * D_)       : knrow;
    const float* rB = (s0 + 1 < PAST_) ? (kbase + (size_t)(s0 + 1) * D_) : knrow;
    float4 nA0 = *(const float4*)(rA + m * 4);
    float4 nA1 = *(const float4*)(rA + 64 + m * 4);
    float4 nA2 = *(const float4*)(rA + 128 + m * 4);
    float4 nA3 = *(const float4*)(rA + 192 + m * 4);
    float4 nB0 = *(const float4*)(rB + m * 4);
    float4 nB1 = *(const float4*)(rB + 64 + m * 4);
    float4 nB2 = *(const float4*)(rB + 128 + m * 4);
    float4 nB3 = *(const float4*)(rB + 192 + m * 4);

    for (int it = 0; it < 8; ++it) {
        int sA = s0 + 2 * it;
        float4 cA0 = nA0, cA1 = nA1, cA2 = nA2, cA3 = nA3;
        float4 cB0 = nB0, cB1 = nB1, cB2 = nB2, cB3 = nB3;
        if (it < 7) {
            int sn = sA + 2;
            const float* pA = (sn     < PAST_) ? (kbase + (size_t)sn * D_)       : knrow;
            const float* pB = (sn + 1 < PAST_) ? (kbase + (size_t)(sn + 1) * D_) : knrow;
            nA0 = *(const float4*)(pA + m * 4);
            nA1 = *(const float4*)(pA + 64 + m * 4);
            nA2 = *(const float4*)(pA + 128 + m * 4);
            nA3 = *(const float4*)(pA + 192 + m * 4);
            nB0 = *(const float4*)(pB + m * 4);
            nB1 = *(const float4*)(pB + 64 + m * 4);
            nB2 = *(const float4*)(pB + 128 + m * 4);
            nB3 = *(const float4*)(pB + 192 + m * 4);
        }
        float fullA = 0.f, apprA = 0.f, fullB = 0.f, apprB = 0.f;
        fullA += qr[0]*cA0.x + qr[1]*cA0.y + qr[2]*cA0.z + qr[3]*cA0.w;
        apprA += ar[0]*cA0.x + ar[1]*cA0.y + ar[2]*cA0.z + ar[3]*cA0.w;
        fullA += qr[4]*cA1.x + qr[5]*cA1.y + qr[6]*cA1.z + qr[7]*cA1.w;
        apprA += ar[4]*cA1.x + ar[5]*cA1.y + ar[6]*cA1.z + ar[7]*cA1.w;
        fullA += qr[8]*cA2.x + qr[9]*cA2.y + qr[10]*cA2.z + qr[11]*cA2.w;
        apprA += ar[8]*cA2.x + ar[9]*cA2.y + ar[10]*cA2.z + ar[11]*cA2.w;
        fullA += qr[12]*cA3.x + qr[13]*cA3.y + qr[14]*cA3.z + qr[15]*cA3.w;
        apprA += ar[12]*cA3.x + ar[13]*cA3.y + ar[14]*cA3.z + ar[15]*cA3.w;
        fullB += qr[0]*cB0.x + qr[1]*cB0.y + qr[2]*cB0.z + qr[3]*cB0.w;
        apprB += ar[0]*cB0.x + ar[1]*cB0.y + ar[2]*cB0.z + ar[3]*cB0.w;
        fullB += qr[4]*cB1.x + qr[5]*cB1.y + qr[6]*cB1.z + qr[7]*cB1.w;
        apprB += ar[4]*cB1.x + ar[5]*cB1.y + ar[6]*cB1.z + ar[7]*cB1.w;
        fullB += qr[8]*cB2.x + qr[9]*cB2.y + qr[10]*cB2.z + qr[11]*cB2.w;
        apprB += ar[8]*cB2.x + ar[9]*cB2.y + ar[10]*cB2.z + ar[11]*cB2.w;
        fullB += qr[12]*cB3.x + qr[13]*cB3.y + qr[14]*cB3.z + qr[15]*cB3.w;
        apprB += ar[12]*cB3.x + ar[13]*cB3.y + ar[14]*cB3.z + ar[15]*cB3.w;
#pragma unroll
        for (int off = 1; off < 16; off <<= 1) {
            fullA += __shfl_xor(fullA, off, 64);
            apprA += __shfl_xor(apprA, off, 64);
            fullB += __shfl_xor(fullB, off, 64);
            apprB += __shfl_xor(apprB, off, 64);
        }
        float2 mv = *(const float2*)(mrow + sA);
        if (m == 0) {
            float2 o; o.x = fullA * 0.0625f + mv.x; o.y = fullB * 0.0625f + mv.y;
            *(float2*)(fout + sA) = o;
        } else if (m == 1) {
            float2 o; o.x = apprA * inv_scale + mv.x; o.y = apprB * inv_scale + mv.y;
            *(float2*)(aout + sA) = o;
        }
    }
}

// ---------------- K3: radix-select top-2048 + softmax -> probs ----------------
#define PAD(s) ((s) + ((s) >> 5))
__global__ __launch_bounds__(1024) void k3_select(
    const float* __restrict__ fsc, const float* __restrict__ asc, float* __restrict__ probs)
{
    int bh = blockIdx.x;
    int t  = threadIdx.x;
    int lane = t & 63, wid = t >> 6;
    __shared__ unsigned ua[8448];        // 8192 + 256 pad words
    __shared__ unsigned hist2[16 * 257]; // per-wave histograms, row-padded
    __shared__ unsigned hist[256];
    __shared__ unsigned sf[256];
    __shared__ int wsum[16], wbase[16];
    __shared__ float wred[16];
    __shared__ unsigned sh_bin; __shared__ int sh_rem;
    __shared__ float sh_M, sh_Z;

    const float* ap = asc + (size_t)bh * S_;
    const float* fp = fsc + (size_t)bh * S_;

#pragma unroll
    for (int i = 0; i < 8; ++i) {
        int s = i * 1024 + t;
        unsigned u = __float_as_uint(ap[s]);
        u ^= (u & 0x80000000u) ? 0xFFFFFFFFu : 0x80000000u;  // order-preserving map
        ua[PAD(s)] = u;
    }

    unsigned prefix = 0; int rem = KKEEP_;
    for (int pass = 0; pass < 4; ++pass) {
        const int shift = 24 - 8 * pass;
        for (int j = t; j < 16 * 257; j += 1024) hist2[j] = 0;
        __syncthreads();
#pragma unroll
        for (int i = 0; i < 8; ++i) {
            unsigned u = ua[PAD(i * 1024 + t)];
            bool match = (pass == 0) || ((u >> (shift + 8)) == prefix);
            if (match) atomicAdd(&hist2[wid * 257 + ((u >> shift) & 255u)], 1u);
        }
        __syncthreads();
        if (t < 256) {
            unsigned hsum = 0;
#pragma unroll
            for (int w2 = 0; w2 < 16; ++w2) hsum += hist2[w2 * 257 + t];
            hist[t] = hsum;
        }
        __syncthreads();
        if (t < 64) {  // wave 0: suffix-sum of 256 bins via shuffles
            unsigned h0 = hist[t*4], h1 = hist[t*4+1], h2 = hist[t*4+2], h3 = hist[t*4+3];
            unsigned loc = h0 + h1 + h2 + h3;
            unsigned run = loc;
#pragma unroll
            for (int off = 1; off < 64; off <<= 1) {
                unsigned v = __shfl_down(run, off, 64);
                if (t + off < 64) run += v;
            }
            unsigned tail = run - loc;   // sum over lanes > me
            sf[t*4+3] = tail + h3;
            sf[t*4+2] = tail + h3 + h2;
            sf[t*4+1] = tail + h3 + h2 + h1;
            sf[t*4+0] = tail + loc;
        }
        __syncthreads();
        if (t < 256) {
            unsigned above = (t == 255) ? 0u : sf[t + 1];
            if (sf[t] >= (unsigned)rem && above < (unsigned)rem) {
                sh_bin = (unsigned)t;
                sh_rem = rem - (int)above;
            }
        }
        __syncthreads();
        prefix = (prefix << 8) | sh_bin;
        rem = sh_rem;
        __syncthreads();
    }
    unsigned ut = prefix; int Need = rem;

    // stable tie-break on contiguous per-thread chunks [t*8, t*8+8)
    int cnt = 0;
#pragma unroll
    for (int i = 0; i < 8; ++i)
        cnt += (ua[PAD(t * 8 + i)] == ut) ? 1 : 0;
    int inc = cnt;
#pragma unroll
    for (int off = 1; off < 64; off <<= 1) {
        int v = __shfl_up(inc, off, 64);
        if (lane >= off) inc += v;
    }
    if (lane == 63) wsum[wid] = inc;
    __syncthreads();
    if (t == 0) {
        int run = 0;
#pragma unroll
        for (int j = 0; j < 16; ++j) { int c = wsum[j]; wbase[j] = run; run += c; }
    }
    __syncthreads();
    int eqb = wbase[wid] + inc - cnt;   // exclusive index-ordered rank among ties
#pragma unroll
    for (int i = 0; i < 8; ++i) {
        int s = t * 8 + i;
        if (ua[PAD(s)] == ut) {
            ua[PAD(s)] = (eqb < Need) ? 0xFFFFFFFFu : 0u;  // sentinel keep/drop
            ++eqb;
        }
    }
    __syncthreads();

    // online softmax over kept elements (coalesced)
    float m = -3.4e38f, z = 0.f;
#pragma unroll
    for (int i = 0; i < 8; ++i) {
        int s = i * 1024 + t;
        if (ua[PAD(s)] > ut) {
            float f = fp[s];
            if (f > m) { z = z * expf(m - f) + 1.f; m = f; }
            else       { z += expf(f - m); }
        }
    }
    float wm = m;
#pragma unroll
    for (int off = 1; off < 64; off <<= 1) wm = fmaxf(wm, __shfl_xor(wm, off, 64));
    if (lane == 0) wred[wid] = wm;
    __syncthreads();
    if (t == 0) {
        float M = wred[0];
#pragma unroll
        for (int j = 1; j < 16; ++j) M = fmaxf(M, wred[j]);
        sh_M = M;
    }
    __syncthreads();
    float M = sh_M;
    float zs = z * expf(m - M);
#pragma unroll
    for (int off = 1; off < 64; off <<= 1) zs += __shfl_xor(zs, off, 64);
    if (lane == 0) wred[wid] = zs;
    __syncthreads();
    if (t == 0) {
        float Z = 0.f;
#pragma unroll
        for (int j = 0; j < 16; ++j) Z += wred[j];
        sh_Z = Z;
    }
    __syncthreads();
    float invZ = 1.0f / sh_Z;

    float* pp = probs + (size_t)bh * S_;
#pragma unroll
    for (int i = 0; i < 8; ++i) {
        int s = i * 1024 + t;
        pp[s] = (ua[PAD(s)] > ut) ? expf(fp[s] - M) * invZ : 0.f;
    }
}

// ---------------- K4: weighted V partial sums (2-row deep prefetch) ----------------
// grid = 16 (b,kvh) * 64 chunks of 128 rows; wave owns 32 contiguous rows,
// 2 rows/iteration.
__global__ __launch_bounds__(256) void k4_wv(
    const float* __restrict__ past_value, const float* __restrict__ vnew,
    const float* __restrict__ probs, float* __restrict__ ypart)
{
    int bkv = blockIdx.x >> 6, chunk = blockIdx.x & 63;
    int b = bkv >> 2, kvh = bkv & 3;
    int w = threadIdx.x >> 6, lane = threadIdx.x & 63;
    int h0 = kvh * 4;

    const float* p0 = probs + (size_t)(b * H_ + h0) * S_;
    const float* vbase = past_value + (size_t)(b * KVH_ + kvh) * PAST_ * D_;
    const float* vnrow = vnew + (b * KVH_ + kvh) * D_;

    float acc[4][4] = {{0.f}};
    int s0 = chunk * 128 + w * 32;   // wave owns rows [s0, s0+32)

    const float* rA = (s0     < PAST_) ? (vbase + (size_t)s0 * D_)       : vnrow;
    const float* rB = (s0 + 1 < PAST_) ? (vbase + (size_t)(s0 + 1) * D_) : vnrow;
    float4 vnA = *(const float4*)(rA + lane * 4);
    float4 vnB = *(const float4*)(rB + lane * 4);
    float2 pn0 = *(const float2*)(p0 + s0);
    float2 pn1 = *(const float2*)(p0 + S_ + s0);
    float2 pn2 = *(const float2*)(p0 + 2 * S_ + s0);
    float2 pn3 = *(const float2*)(p0 + 3 * S_ + s0);

    for (int it = 0; it < 16; ++it) {
        float4 vA = vnA, vB = vnB;
        float2 c0 = pn0, c1 = pn1, c2 = pn2, c3 = pn3;
        if (it < 15) {
            int sn = s0 + 2 * it + 2;
            const float* pA = (sn     < PAST_) ? (vbase + (size_t)sn * D_)       : vnrow;
            const float* pB = (sn + 1 < PAST_) ? (vbase + (size_t)(sn + 1) * D_) : vnrow;
            vnA = *(const float4*)(pA + lane * 4);
            vnB = *(const float4*)(pB + lane * 4);
            pn0 = *(const float2*)(p0 + sn);
            pn1 = *(const float2*)(p0 + S_ + sn);
            pn2 = *(const float2*)(p0 + 2 * S_ + sn);
            pn3 = *(const float2*)(p0 + 3 * S_ + sn);
        }
        acc[0][0] += c0.x * vA.x + c0.y * vB.x;
        acc[0][1] += c0.x * vA.y + c0.y * vB.y;
        acc[0][2] += c0.x * vA.z + c0.y * vB.z;
        acc[0][3] += c0.x * vA.w + c0.y * vB.w;
        acc[1][0] += c1.x * vA.x + c1.y * vB.x;
        acc[1][1] += c1.x * vA.y + c1.y * vB.y;
        acc[1][2] += c1.x * vA.z + c1.y * vB.z;
        acc[1][3] += c1.x * vA.w + c1.y * vB.w;
        acc[2][0] += c2.x * vA.x + c2.y * vB.x;
        acc[2][1] += c2.x * vA.y + c2.y * vB.y;
        acc[2][2] += c2.x * vA.z + c2.y * vB.z;
        acc[2][3] += c2.x * vA.w + c2.y * vB.w;
        acc[3][0] += c3.x * vA.x + c3.y * vB.x;
        acc[3][1] += c3.x * vA.y + c3.y * vB.y;
        acc[3][2] += c3.x * vA.z + c3.y * vB.z;
        acc[3][3] += c3.x * vA.w + c3.y * vB.w;
    }

    __shared__ float part[4][4][256];   // [wave][head][dim]
#pragma unroll
    for (int j = 0; j < 4; ++j)
#pragma unroll
        for (int t4 = 0; t4 < 4; ++t4)
            part[w][j][lane * 4 + t4] = acc[j][t4];
    __syncthreads();

    float* yo = ypart + (size_t)(chunk * 16 + bkv) * 1024;
    for (int o = threadIdx.x; o < 1024; o += 256) {
        int j = o >> 8, d = o & 255;
        yo[o] = part[0][j][d] + part[1][j][d] + part[2][j][d] + part[3][j][d];
    }
}

// ---------------- K5: reduce partials -> y flat ----------------
__global__ __launch_bounds__(256) void k5_reduce(const float* __restrict__ ypart, float* __restrict__ yflat)
{
    int bh = blockIdx.x; int b = bh >> 4, h = bh & 15;
    int kvh = h >> 2, j = h & 3;
    int d = threadIdx.x;
    int bkv = b * 4 + kvh;
    float sum = 0.f;
    for (int c = 0; c < 64; ++c)
        sum += ypart[(size_t)(c * 16 + bkv) * 1024 + j * 256 + d];
    yflat[b * 4096 + h * 256 + d] = sum;
}

// ---------------- K6: output projection GEMV ----------------
__global__ __launch_bounds__(256) void k6_out(
    const float* __restrict__ Wo, const float* __restrict__ yflat, float* __restrict__ out)
{
    int i = blockIdx.x;
    const float* wrow = Wo + (size_t)i * HID_;
    float acc[4] = {0.f, 0.f, 0.f, 0.f};
#pragma unroll
    for (int ii = 0; ii < 4; ++ii) {
        int c = (threadIdx.x + 256 * ii) * 4;
        float4 wv = *(const float4*)(wrow + c);
#pragma unroll
        for (int b = 0; b < 4; ++b) {
            float4 yv = *(const float4*)(yflat + b * 4096 + c);
            acc[b] += wv.x * yv.x + wv.y * yv.y + wv.z * yv.z + wv.w * yv.w;
        }
    }
#pragma unroll
    for (int off = 1; off < 64; off <<= 1)
#pragma unroll
        for (int b = 0; b < 4; ++b) acc[b] += __shfl_xor(acc[b], off, 64);
    __shared__ float red[4][4];
    int wv_ = threadIdx.x >> 6, ln = threadIdx.x & 63;
    if (ln == 0)
#pragma unroll
        for (int b = 0; b < 4; ++b) red[wv_][b] = acc[b];
    __syncthreads();
    if (threadIdx.x < 4) {
        int b = threadIdx.x;
        out[b * HID_ + i] = red[0][b] + red[1][b] + red[2][b] + red[3][b];
    }
}

extern "C" void kernel_launch(void* const* d_in, const int* in_sizes, int n_in,
                              void* d_out, int out_size, void* d_ws, size_t ws_size,
                              hipStream_t stream)
{
    const float* hidden = (const float*)d_in[0];
    const float* amask  = (const float*)d_in[1];
    const int*   posids = (const int*)d_in[2];
    const float* pkey   = (const float*)d_in[3];
    const float* pval   = (const float*)d_in[4];
    const float* Wq     = (const float*)d_in[5];
    const float* Wk     = (const float*)d_in[6];
    const float* Wv     = (const float*)d_in[7];
    const float* Wo     = (const float*)d_in[8];
    float* out = (float*)d_out;
    float* ws  = (float*)d_ws;

    float* q_ws   = ws + OFF_Q;
    float* knew   = ws + OFF_KN;
    float* vnew   = ws + OFF_VN;
    float* scale  = ws + OFF_SCALE;
    unsigned* cmask = (unsigned*)(ws + OFF_CMASK);
    float* fsc    = ws + OFF_F;
    float* asc    = ws + OFF_A;
    float* probs  = ws + OFF_P;
    float* ypart  = ws + OFF_YP;
    float* yflat  = ws + OFF_Y;

    k1_qkv  <<<dim3(3072), dim3(256), 0, stream>>>(hidden, posids, Wq, Wk, Wv, q_ws, knew, vnew);
    k1b_chan<<<dim3(64),   dim3(256), 0, stream>>>(q_ws, scale, cmask);
    k2_scores<<<dim3(2048), dim3(256), 0, stream>>>(pkey, knew, q_ws, scale, cmask, amask, fsc, asc);
    k3_select<<<dim3(64),  dim3(1024), 0, stream>>>(fsc, asc, probs);
    k4_wv   <<<dim3(1024), dim3(256), 0, stream>>>(pval, vnew, probs, ypart);
    k5_reduce<<<dim3(64),  dim3(256), 0, stream>>>(ypart, yflat);
    k6_out  <<<dim3(4096), dim3(256), 0, stream>>>(Wo, yflat, out);
}